// Round 8
// baseline (498.623 us; speedup 1.0000x reference)
//
#include <hip/hip_runtime.h>
#include <math.h>

#define NN 100000
#define EE 1600000
#define D 128
#define NBK 3125          // buckets of 32 rows == fused blocks (NN/32)
#define SBLK 98           // scatter blocks
#define EPB 16384         // edges per scatter block (98*16384 >= EE)
#define CAP 1024          // fixed arena slots per bucket (max count ~603 at 18 sigma)

typedef __attribute__((ext_vector_type(8))) short short8;
typedef __attribute__((ext_vector_type(4))) float floatx4;

// ---------- helpers ----------
static __device__ __forceinline__ unsigned short f2bf(float f) {
  unsigned int u = __builtin_bit_cast(unsigned int, f);
  u = (u + 0x7fff + ((u >> 16) & 1)) >> 16;   // RNE
  return (unsigned short)u;
}
static __device__ __forceinline__ unsigned int pk2(float a, float b) {
  return (unsigned int)f2bf(a) | ((unsigned int)f2bf(b) << 16);
}
static __device__ __forceinline__ float bflo(unsigned int u) { return __builtin_bit_cast(float, u << 16); }
static __device__ __forceinline__ float bfhi(unsigned int u) { return __builtin_bit_cast(float, u & 0xffff0000u); }
static __device__ __forceinline__ float bf2f(unsigned short s) {
  return __builtin_bit_cast(float, (unsigned int)s << 16);
}
static __device__ __forceinline__ float sig_f(float x) { return 1.f / (1.f + __expf(-x)); }
static __device__ __forceinline__ float tanh_f(float x) {
  float e = __expf(2.f * x);
  return 1.f - 2.f / (e + 1.f);
}
static __device__ __forceinline__ void fma8(float* acc, float w, uint4 h) {
  acc[0] += w * bflo(h.x); acc[1] += w * bfhi(h.x);
  acc[2] += w * bflo(h.y); acc[3] += w * bfhi(h.y);
  acc[4] += w * bflo(h.z); acc[5] += w * bfhi(h.z);
  acc[6] += w * bflo(h.w); acc[7] += w * bfhi(h.w);
}

// ================= launch 1: one-pass bucket scatter (atomic run-reservation) + weight packing =================
// blocks 0..97:  LDS hist over 3125 buckets -> one global atomicAdd per (block,bucket) reserves a
//                contiguous run at b*CAP + off -> LDS-cursor write-combined scatter.
//                bucket_len[b] ends as the final bucket count (fused reads it).
// blocks 98..109: pack ugW/rgW/CW/W into MFMA B-fragment order.
__global__ __launch_bounds__(1024) void scatterpack(
    const int* __restrict__ erow, const int* __restrict__ ecol, const float* __restrict__ ew,
    int* __restrict__ bucket_len, int2* __restrict__ arena,
    const float* __restrict__ ugW, const float* __restrict__ rgW,
    const float* __restrict__ CW, const float* __restrict__ W,
    unsigned int* __restrict__ packZR, unsigned int* __restrict__ packCW,
    unsigned int* __restrict__ packW) {
  __shared__ int cur[NBK];
  const int tid = threadIdx.x;
  if (blockIdx.x < SBLK) {
    for (int b = tid; b < NBK; b += 1024) cur[b] = 0;
    __syncthreads();
    const int base = blockIdx.x * EPB;
    int r[16];
#pragma unroll
    for (int i = 0; i < 16; ++i) {
      int idx = base + i * 1024 + tid;
      r[i] = (idx < EE) ? erow[idx] : -1;
      if (r[i] >= 0) atomicAdd(&cur[r[i] >> 5], 1);
    }
    __syncthreads();
    for (int b = tid; b < NBK; b += 1024) {
      int c = cur[b];
      cur[b] = c ? (b * CAP + atomicAdd(&bucket_len[b], c)) : 0;
    }
    __syncthreads();
#pragma unroll
    for (int i = 0; i < 16; ++i) {
      if (r[i] >= 0) {
        int idx = base + i * 1024 + tid;
        int pos = atomicAdd(&cur[r[i] >> 5], 1);
        int2 v;
        v.x = ecol[idx] | ((r[i] & 31) << 24);   // col fits 17 bits; row-local 5 bits in 24..28
        v.y = __builtin_bit_cast(int, ew[idx]);
        arena[pos] = v;
      }
    }
  } else {
    int g = (blockIdx.x - SBLK) * 16 + (tid >> 6);
    int lane = tid & 63;
    if (g < 128) {
      int nt = g >> 3, ks = g & 7;
      int o = nt * 16 + (lane & 15);
      int c0 = ks * 32 + (lane >> 4) * 8;
      const float* src = (o < 128 ? ugW + (size_t)o * 256 : rgW + (size_t)(o - 128) * 256) + c0;
      float4 f0 = ((const float4*)src)[0];
      float4 f1 = ((const float4*)src)[1];
      uint4 out;
      out.x = pk2(f0.x, f0.y);
      out.y = pk2(f0.z, f0.w);
      out.z = pk2(f1.x, f1.y);
      out.w = pk2(f1.z, f1.w);
      ((uint4*)packZR)[g * 64 + lane] = out;
    } else if (g < 192) {
      const float* M = (g < 160) ? CW : W;
      unsigned int* dst = (g < 160) ? packCW : packW;
      int gg = (g < 160) ? (g - 128) : (g - 160);
      int nt = gg >> 2, ks = gg & 3;
      int n = nt * 16 + (lane & 15);
      int k0 = ks * 32 + (lane >> 4) * 8;
      unsigned short v[8];
#pragma unroll
      for (int j = 0; j < 8; ++j) v[j] = f2bf(M[(size_t)(k0 + j) * 128 + n]);
      uint4 out;
      out.x = (unsigned int)v[0] | ((unsigned int)v[1] << 16);
      out.y = (unsigned int)v[2] | ((unsigned int)v[3] << 16);
      out.z = (unsigned int)v[4] | ((unsigned int)v[5] << 16);
      out.w = (unsigned int)v[6] | ((unsigned int)v[7] << 16);
      ((uint4*)dst)[gg * 64 + lane] = out;
    }
  }
}

// ================= launch 2: h0 = X @ W + b via MFMA (bf16 master) =================
__global__ __launch_bounds__(256) void init_mfma(
    const float* __restrict__ X, const short* __restrict__ packW, const float* __restrict__ bias,
    unsigned short* __restrict__ h_bf) {
  __shared__ __align__(16) short sX[32 * 136];
  const int tid = threadIdx.x;
  const int row0 = blockIdx.x * 32;

  {
    int r = tid >> 3, ch = tid & 7;
    const float4* px = (const float4*)(X + (size_t)(row0 + r) * D + ch * 16);
    float4 f0 = px[0], f1 = px[1], f2 = px[2], f3 = px[3];
    uint4 o0, o1;
    o0.x = pk2(f0.x, f0.y); o0.y = pk2(f0.z, f0.w);
    o0.z = pk2(f1.x, f1.y); o0.w = pk2(f1.z, f1.w);
    o1.x = pk2(f2.x, f2.y); o1.y = pk2(f2.z, f2.w);
    o1.z = pk2(f3.x, f3.y); o1.w = pk2(f3.z, f3.w);
    *(uint4*)(sX + r * 136 + ch * 16) = o0;
    *(uint4*)(sX + r * 136 + ch * 16 + 8) = o1;
  }
  __syncthreads();

  const int wave = tid >> 6, lane = tid & 63;
  const int quad = lane >> 4, l15 = lane & 15;
  const int mh = wave & 1, nh = wave >> 1;
  const int mrow = mh * 16 + l15;

  floatx4 acc[4];
  const floatx4 zero4 = {0.f, 0.f, 0.f, 0.f};
#pragma unroll
  for (int t = 0; t < 4; ++t) acc[t] = zero4;

  const short8* pW = (const short8*)packW;
#pragma unroll
  for (int ks = 0; ks < 4; ++ks) {
    short8 a = *(const short8*)(sX + mrow * 136 + ks * 32 + quad * 8);
#pragma unroll
    for (int t = 0; t < 4; ++t) {
      short8 b = pW[((nh * 4 + t) * 4 + ks) * 64 + lane];
      acc[t] = __builtin_amdgcn_mfma_f32_16x16x32_bf16(a, b, acc[t], 0, 0, 0);
    }
  }

  __syncthreads();   // all waves done reading sX before in-place overwrite
#pragma unroll
  for (int t = 0; t < 4; ++t) {
    int col = nh * 64 + t * 16 + l15;
    float bv = bias[col];
#pragma unroll
    for (int reg = 0; reg < 4; ++reg) {
      int row = mh * 16 + quad * 4 + reg;
      sX[row * 136 + col] = (short)f2bf(acc[t][reg] + bv);
    }
  }
  __syncthreads();
  for (int idx = tid; idx < 512; idx += 256) {
    int r = idx >> 4, ch = idx & 15;
    *(uint4*)(h_bf + (size_t)(row0 + r) * D + ch * 8) = *(uint4*)(sX + r * 136 + ch * 8);
  }
}

// ================= fused step: in-LDS row-sort + gather + gates + candidate + h update =================
// 512 threads = 8 waves per 32-row block == one bucket.
// Gather: stage bucket's arena segment (<=CAP) into LDS, counting-sort by 5-bit row tag
//         (hist + shfl-scan + scatter ~ hidden under gather BW stalls), then one row per
//         16-lane subgroup walks its sorted run. No row_start array, no separate sort pass.
__global__ __launch_bounds__(512, 8) void fused_step(
    const int* __restrict__ bucket_len, const int2* __restrict__ arena,
    const uint4* __restrict__ h4,                         // h_in, bf16 rows (16 uint4 each)
    const short* __restrict__ packZR, const short* __restrict__ packCW,
    const float* __restrict__ ugb, const float* __restrict__ rgb,
    unsigned short* __restrict__ h_bf_out, float* __restrict__ h_f32_out, int last) {
  __shared__ __align__(16) short sA[32 * 264];            // [row][c] = [h(128) | m(128)], stride 264
  __shared__ __align__(16) char sU[8704];                 // phase A: sE_raw int2[1024]; phase B: sRH[32*136]
  __shared__ __align__(16) int2 sE2[CAP];                 // sorted edges
  __shared__ int rcnt[32];
  __shared__ int rstart[32];
  __shared__ int rcur[32];
  int2* sE_raw = (int2*)sU;
  short* sRH = (short*)sU;

  const int tid = threadIdx.x;
  const int bid = blockIdx.x;
  const int row0 = bid * 32;
  const int wave = tid >> 6, lane = tid & 63;
  const int sub = lane >> 4, li = lane & 15;

  // ---- stage this block's h rows (coalesced) ----
  {
    int r = tid >> 4, ch = tid & 15;                      // 512 threads -> 32 rows x 16 uint4
    *(uint4*)(sA + r * 264 + ch * 8) = h4[(size_t)(row0 + r) * 16 + ch];
  }

  // ---- load + counting-sort the bucket's edge segment ----
  const int lo = bid * CAP;
  int len = bucket_len[bid];
  len = (len < CAP) ? len : CAP;                          // capacity guard (never hit for this input)

  if (tid < 32) rcnt[tid] = 0;
  for (int i = tid; i < len; i += 512) sE_raw[i] = arena[lo + i];
  __syncthreads();
  for (int i = tid; i < len; i += 512) atomicAdd(&rcnt[(sE_raw[i].x >> 24) & 31], 1);
  __syncthreads();
  if (tid < 64) {                                         // wave 0: exclusive scan of 32 counts
    int v = (tid < 32) ? rcnt[tid] : 0;
    int inc = v;
#pragma unroll
    for (int d = 1; d < 32; d <<= 1) {
      int u = __shfl_up(inc, d, 64);
      if (tid >= d) inc += u;
    }
    if (tid < 32) { rstart[tid] = inc - v; rcur[tid] = inc - v; }
  }
  __syncthreads();
  for (int i = tid; i < len; i += 512) {
    int2 e = sE_raw[i];
    int pos = atomicAdd(&rcur[(e.x >> 24) & 31], 1);
    sE2[pos] = e;
  }
  __syncthreads();

  // ---- gather: one row per 16-lane subgroup, sorted run from LDS ----
  const int rl = wave * 4 + sub;
  float acc[8];
#pragma unroll
  for (int j = 0; j < 8; ++j) acc[j] = 0.f;

  int kb = rstart[rl];
  int ke = kb + rcnt[rl];
  for (; kb + 2 <= ke; kb += 2) {
    int2 e0 = sE2[kb];
    int2 e1 = sE2[kb + 1];
    uint4 h0 = h4[(size_t)(e0.x & 0x00FFFFFF) * 16 + li];
    uint4 h1 = h4[(size_t)(e1.x & 0x00FFFFFF) * 16 + li];
    fma8(acc, __builtin_bit_cast(float, e0.y), h0);
    fma8(acc, __builtin_bit_cast(float, e1.y), h1);
  }
  if (kb < ke) {
    int2 e0 = sE2[kb];
    uint4 h0 = h4[(size_t)(e0.x & 0x00FFFFFF) * 16 + li];
    fma8(acc, __builtin_bit_cast(float, e0.y), h0);
  }

  // writeback m: each subgroup writes its full row (16 lanes x 16B = 256B)
  {
    uint4 o;
    o.x = pk2(acc[0], acc[1]);
    o.y = pk2(acc[2], acc[3]);
    o.z = pk2(acc[4], acc[5]);
    o.w = pk2(acc[6], acc[7]);
    *(uint4*)(sA + (wave * 4 + sub) * 264 + 128 + li * 8) = o;
  }
  __syncthreads();

  // ---- gates: z and r for this wave's 16x32 tile ----
  const int quad = lane >> 4, l15 = lane & 15;
  const int mh = wave >> 2, nh = wave & 3;
  const int mrow = mh * 16 + l15;

  floatx4 accZ[2], accR[2];
  const floatx4 zero4 = {0.f, 0.f, 0.f, 0.f};
#pragma unroll
  for (int t = 0; t < 2; ++t) { accZ[t] = zero4; accR[t] = zero4; }

  const short8* pB = (const short8*)packZR;
#pragma unroll
  for (int ks = 0; ks < 8; ++ks) {
    short8 a = *(const short8*)(sA + mrow * 264 + ks * 32 + quad * 8);
#pragma unroll
    for (int t = 0; t < 2; ++t) {
      short8 bz = pB[((nh * 2 + t) * 8 + ks) * 64 + lane];
      accZ[t] = __builtin_amdgcn_mfma_f32_16x16x32_bf16(a, bz, accZ[t], 0, 0, 0);
      short8 br = pB[((8 + nh * 2 + t) * 8 + ks) * 64 + lane];
      accR[t] = __builtin_amdgcn_mfma_f32_16x16x32_bf16(a, br, accR[t], 0, 0, 0);
    }
  }

  // epilogue 1: z -> registers (overwrite accZ), rh -> sRH
#pragma unroll
  for (int t = 0; t < 2; ++t) {
    int col = nh * 32 + t * 16 + l15;
    float zb = ugb[col], rb = rgb[col];
#pragma unroll
    for (int reg = 0; reg < 4; ++reg) {
      int row = mh * 16 + quad * 4 + reg;
      float z = sig_f(accZ[t][reg] + zb);
      float rr = sig_f(accR[t][reg] + rb);
      float hv = bf2f((unsigned short)sA[row * 264 + col]);
      sRH[row * 136 + col] = (short)f2bf(rr * hv);
      accZ[t][reg] = z;
    }
  }
  __syncthreads();

  // ---- cand = tanh((r*h) @ CW) ----
  floatx4 acc2[2];
#pragma unroll
  for (int t = 0; t < 2; ++t) acc2[t] = zero4;

  const short8* pC = (const short8*)packCW;
#pragma unroll
  for (int ks = 0; ks < 4; ++ks) {
    short8 a = *(const short8*)(sRH + mrow * 136 + ks * 32 + quad * 8);
#pragma unroll
    for (int t = 0; t < 2; ++t) {
      short8 b = pC[((nh * 2 + t) * 4 + ks) * 64 + lane];
      acc2[t] = __builtin_amdgcn_mfma_f32_16x16x32_bf16(a, b, acc2[t], 0, 0, 0);
    }
  }

  // final: h' = z*h + (1-z)*cand   (z regs align with acc2 layout exactly)
#pragma unroll
  for (int t = 0; t < 2; ++t) {
    int col = nh * 32 + t * 16 + l15;
#pragma unroll
    for (int reg = 0; reg < 4; ++reg) {
      int row = mh * 16 + quad * 4 + reg;
      float cand = tanh_f(acc2[t][reg]);
      float z = accZ[t][reg];
      float hold = bf2f((unsigned short)sA[row * 264 + col]);
      float hn = z * hold + (1.f - z) * cand;
      if (last) h_f32_out[(size_t)(row0 + row) * D + col] = hn;
      else sA[row * 264 + col] = (short)f2bf(hn);         // in-place; own element only
    }
  }
  if (!last) {
    __syncthreads();
    // coalesced full-row bf16 stores (256B lines)
    int r = tid >> 4, ch = tid & 15;
    *(uint4*)(h_bf_out + (size_t)(row0 + r) * D + ch * 8) = *(uint4*)(sA + r * 264 + ch * 8);
  }
}

extern "C" void kernel_launch(void* const* d_in, const int* in_sizes, int n_in,
                              void* d_out, int out_size, void* d_ws, size_t ws_size,
                              hipStream_t stream) {
  const float* input = (const float*)d_in[0];
  const int* erow    = (const int*)d_in[1];
  const int* ecol    = (const int*)d_in[2];
  const float* ew    = (const float*)d_in[3];
  const float* W     = (const float*)d_in[4];
  const float* bias  = (const float*)d_in[5];
  const float* CW    = (const float*)d_in[6];
  const float* ugW   = (const float*)d_in[7];
  const float* ugb   = (const float*)d_in[8];
  const float* rgW   = (const float*)d_in[9];
  const float* rgb   = (const float*)d_in[10];

  float* h_out = (float*)d_out;

  // ---- workspace carve-up (~77 MB) ----
  char* ws = (char*)d_ws;
  unsigned short* hA = (unsigned short*)ws;   ws += (size_t)NN * D * 2;            // 25.6 MB (h ping)
  unsigned short* hB = (unsigned short*)ws;   ws += (size_t)NN * D * 2;            // 25.6 MB (h pong)
  unsigned int* packZR = (unsigned int*)ws;   ws += 16 * 8 * 64 * 16;              // 128 KB
  unsigned int* packCW = (unsigned int*)ws;   ws += 8 * 4 * 64 * 16;               // 32 KB
  unsigned int* packW  = (unsigned int*)ws;   ws += 8 * 4 * 64 * 16;               // 32 KB
  int2* arena    = (int2*)ws;                 ws += (size_t)NBK * CAP * sizeof(int2); // 25.6 MB
  int* bucket_len= (int*)ws;                  ws += NBK * sizeof(int);             // 12.5 KB

  // ---- one-pass CSR-lite build + packing + init (3 launches + memset) ----
  hipMemsetAsync(bucket_len, 0, NBK * sizeof(int), stream);
  scatterpack<<<SBLK + 12, 1024, 0, stream>>>(erow, ecol, ew, bucket_len, arena,
                                              ugW, rgW, CW, W, packZR, packCW, packW);
  init_mfma<<<NN / 32, 256, 0, stream>>>(input, (const short*)packW, bias, hA);

  // ---- fused steps, h double-buffered (gather reads other blocks' rows) ----
  fused_step<<<NBK, 512, 0, stream>>>(bucket_len, arena, (const uint4*)hA,
                                      (const short*)packZR, (const short*)packCW,
                                      ugb, rgb, hB, h_out, 0);
  fused_step<<<NBK, 512, 0, stream>>>(bucket_len, arena, (const uint4*)hB,
                                      (const short*)packZR, (const short*)packCW,
                                      ugb, rgb, hA, h_out, 0);
  fused_step<<<NBK, 512, 0, stream>>>(bucket_len, arena, (const uint4*)hA,
                                      (const short*)packZR, (const short*)packCW,
                                      ugb, rgb, hB, h_out, 1);
}